// Round 3
// baseline (473.881 us; speedup 1.0000x reference)
//
#include <hip/hip_runtime.h>
#include <hip/hip_bf16.h>

typedef __attribute__((ext_vector_type(8))) short short8;   // 8 x bf16 = 4 VGPRs
typedef __attribute__((ext_vector_type(4))) float floatx4;  // MFMA C/D

// total ordering: larger value wins; tie -> smaller index wins (jax.lax.top_k)
__device__ __forceinline__ bool better(float va, int ia, float vb, int ib) {
    return (va > vb) || (va == vb && ia < ib);
}
__device__ __forceinline__ bool betterd(double va, int ia, double vb, int ib) {
    return (va > vb) || (va == vb && ia < ib);
}

__device__ __forceinline__ short bf16_rn(float f) {
    __hip_bfloat16 h = __float2bfloat16(f);   // round-to-nearest-even
    return *reinterpret_cast<short*>(&h);
}
__device__ __forceinline__ float bf16_up(short s) {
    return __uint_as_float(((unsigned)(unsigned short)s) << 16);
}

// split 8 fp32 into bf16 hi + bf16 lo fragments (a ~= hi + lo)
// NOTE: inputs appear to be bf16-valued fp32, so lo is typically exactly 0
// and the hi products are exact; lo terms kept for robustness.
__device__ __forceinline__ void split8(float4 a, float4 b, short8& hi, short8& lo) {
    float v[8] = {a.x, a.y, a.z, a.w, b.x, b.y, b.z, b.w};
    #pragma unroll
    for (int i = 0; i < 8; ++i) {
        short h = bf16_rn(v[i]);
        hi[i] = h;
        lo[i] = bf16_rn(v[i] - bf16_up(h));
    }
}

#define MFMA(A, B, C) __builtin_amdgcn_mfma_f32_16x16x32_bf16((A), (B), (C), 0, 0, 0)

__global__ __launch_bounds__(256, 4)
void router_kernel(const float* __restrict__ tokens,
                   const int* __restrict__ tarr,
                   const float* __restrict__ Wg,
                   const float* __restrict__ bg,
                   float* __restrict__ out,
                   int* __restrict__ flagCount,
                   int* __restrict__ flagList,
                   int listCap)
{
    __shared__ __align__(16) float gtile[64 * 64];   // 16 KB fp32 gate tile

    const int lane = threadIdx.x & 63;
    const int wave = threadIdx.x >> 6;
    const int c16  = lane & 15;   // expert-within-tile (B col) / token (A row)
    const int quad = lane >> 4;   // k-chunk selector

    const int tokenBase = blockIdx.x * 64;
    const int token     = tokenBase + wave * 16 + c16;

    const float4* ap = reinterpret_cast<const float4*>(tokens) + (size_t)token * 256 + quad * 2;
    const float4* wp0 = reinterpret_cast<const float4*>(Wg) + (size_t)(c16 +  0) * 256 + quad * 2;
    const float4* wp1 = reinterpret_cast<const float4*>(Wg) + (size_t)(c16 + 16) * 256 + quad * 2;
    const float4* wp2 = reinterpret_cast<const float4*>(Wg) + (size_t)(c16 + 32) * 256 + quad * 2;
    const float4* wp3 = reinterpret_cast<const float4*>(Wg) + (size_t)(c16 + 48) * 256 + quad * 2;

    floatx4 acc0 = {0.f, 0.f, 0.f, 0.f};
    floatx4 acc1 = acc0, acc2 = acc0, acc3 = acc0;

    for (int kb = 0; kb < 32; ++kb) {   // 32 k-steps of K=32
        short8 ahi, alo;
        split8(ap[kb * 8], ap[kb * 8 + 1], ahi, alo);
        {
            short8 whi, wlo;
            split8(wp0[kb * 8], wp0[kb * 8 + 1], whi, wlo);
            acc0 = MFMA(ahi, whi, acc0);
            acc0 = MFMA(alo, whi, acc0);
            acc0 = MFMA(ahi, wlo, acc0);
        }
        {
            short8 whi, wlo;
            split8(wp1[kb * 8], wp1[kb * 8 + 1], whi, wlo);
            acc1 = MFMA(ahi, whi, acc1);
            acc1 = MFMA(alo, whi, acc1);
            acc1 = MFMA(ahi, wlo, acc1);
        }
        {
            short8 whi, wlo;
            split8(wp2[kb * 8], wp2[kb * 8 + 1], whi, wlo);
            acc2 = MFMA(ahi, whi, acc2);
            acc2 = MFMA(alo, whi, acc2);
            acc2 = MFMA(ahi, wlo, acc2);
        }
        {
            short8 whi, wlo;
            split8(wp3[kb * 8], wp3[kb * 8 + 1], whi, wlo);
            acc3 = MFMA(ahi, whi, acc3);
            acc3 = MFMA(alo, whi, acc3);
            acc3 = MFMA(ahi, wlo, acc3);
        }
    }

    const float b0f = bg[c16 +  0];
    const float b1f = bg[c16 + 16];
    const float b2f = bg[c16 + 32];
    const float b3f = bg[c16 + 48];

    const float tb  = (float)tarr[tokenBase >> 12];   // 4096 tokens per batch
    const float cap = 0.5f + 1.1f * (tb / 1000.0f);

    const float A1 = 0.85f;            // 1 - alpha, alpha = 0.15
    const float A2 = 0.15f / 64.0f;    // alpha / E

    #pragma unroll
    for (int r = 0; r < 4; ++r) {
        float l0 = acc0[r] + b0f;
        float l1 = acc1[r] + b1f;
        float l2 = acc2[r] + b2f;
        float l3 = acc3[r] + b3f;

        // --- softmax over 64 experts (16-lane group x 4 local) ---
        float mx = fmaxf(fmaxf(l0, l1), fmaxf(l2, l3));
        #pragma unroll
        for (int off = 8; off >= 1; off >>= 1)
            mx = fmaxf(mx, __shfl_xor(mx, off));

        float e0 = expf(l0 - mx), e1 = expf(l1 - mx);
        float e2 = expf(l2 - mx), e3 = expf(l3 - mx);
        float s = e0 + e1 + e2 + e3;
        #pragma unroll
        for (int off = 8; off >= 1; off >>= 1)
            s += __shfl_xor(s, off);
        float inv = 1.0f / s;

        // --- routing floor ---
        float p0 = A1 * (e0 * inv) + A2;
        float p1 = A1 * (e1 * inv) + A2;
        float p2 = A1 * (e2 * inv) + A2;
        float p3 = A1 * (e3 * inv) + A2;

        // --- hard cap with excess redistribution ---
        float x0 = fmaxf(p0 - cap, 0.f), x1 = fmaxf(p1 - cap, 0.f);
        float x2 = fmaxf(p2 - cap, 0.f), x3 = fmaxf(p3 - cap, 0.f);
        float m0 = p0 - x0, m1 = p1 - x1, m2 = p2 - x2, m3 = p3 - x3;
        float h0 = fmaxf(cap - m0, 0.f), h1 = fmaxf(cap - m1, 0.f);
        float h2 = fmaxf(cap - m2, 0.f), h3 = fmaxf(cap - m3, 0.f);
        float sx = x0 + x1 + x2 + x3;
        float sh = h0 + h1 + h2 + h3;
        #pragma unroll
        for (int off = 8; off >= 1; off >>= 1) {
            sx += __shfl_xor(sx, off);
            sh += __shfl_xor(sh, off);
        }
        sh = fmaxf(sh, 1e-8f);
        float sc = sx / sh;
        float c0 = m0 + sc * h0;
        float c1 = m1 + sc * h1;
        float c2 = m2 + sc * h2;
        float c3 = m3 + sc * h3;

        // --- top-2 (value desc, tie -> smaller expert index) ---
        const int iA = c16, iB = c16 + 16, iC = c16 + 32, iD = c16 + 48;
        float v1, v2; int j1, j2;
        if (better(c0, iA, c1, iB)) { v1 = c0; j1 = iA; v2 = c1; j2 = iB; }
        else                        { v1 = c1; j1 = iB; v2 = c0; j2 = iA; }
        if (better(c2, iC, v1, j1))      { v2 = v1; j2 = j1; v1 = c2; j1 = iC; }
        else if (better(c2, iC, v2, j2)) { v2 = c2; j2 = iC; }
        if (better(c3, iD, v1, j1))      { v2 = v1; j2 = j1; v1 = c3; j1 = iD; }
        else if (better(c3, iD, v2, j2)) { v2 = c3; j2 = iD; }

        #pragma unroll
        for (int off = 1; off < 16; off <<= 1) {
            float w1 = __shfl_xor(v1, off); int k1 = __shfl_xor(j1, off);
            float w2 = __shfl_xor(v2, off); int k2 = __shfl_xor(j2, off);
            if (better(w1, k1, v1, j1)) {
                if (better(v1, j1, w2, k2)) { v2 = v1; j2 = j1; }
                else                        { v2 = w2; j2 = k2; }
                v1 = w1; j1 = k1;
            } else if (better(w1, k1, v2, j2)) {
                v2 = w1; j2 = k1;
            }
        }

        float g0 = (iA == j1 || iA == j2) ? c0 : 0.f;
        float g1 = (iB == j1 || iB == j2) ? c1 : 0.f;
        float g2 = (iC == j1 || iC == j2) ? c2 : 0.f;
        float g3 = (iD == j1 || iD == j2) ? c3 : 0.f;

        // --- rank2 vs rank3 margin; flag uncertain tokens for fp64 repair ---
        float t0 = (iA == j1 || iA == j2) ? -3.0e38f : c0;
        float t1 = (iB == j1 || iB == j2) ? -3.0e38f : c1;
        float t2 = (iC == j1 || iC == j2) ? -3.0e38f : c2;
        float t3 = (iD == j1 || iD == j2) ? -3.0e38f : c3;
        float m3v = fmaxf(fmaxf(t0, t1), fmaxf(t2, t3));
        #pragma unroll
        for (int off = 8; off >= 1; off >>= 1)
            m3v = fmaxf(m3v, __shfl_xor(m3v, off));

        const int tl = wave * 16 + quad * 4 + r;   // token within block
        bool flag = ((v2 - m3v) < 1e-4f) || (sx > 0.0f);
        if (flag && c16 == 0) {
            int pos = atomicAdd(flagCount, 1);
            if (pos < listCap) flagList[pos] = tokenBase + tl;
        }

        gtile[tl * 64 + iA] = g0;
        gtile[tl * 64 + iB] = g1;
        gtile[tl * 64 + iC] = g2;
        gtile[tl * 64 + iD] = g3;
    }

    __syncthreads();

    const uint4* src = reinterpret_cast<const uint4*>(gtile);
    uint4* dst = reinterpret_cast<uint4*>(out + (size_t)tokenBase * 64);
    dst[threadIdx.x]       = src[threadIdx.x];
    dst[threadIdx.x + 256] = src[threadIdx.x + 256];
    dst[threadIdx.x + 512] = src[threadIdx.x + 512];
    dst[threadIdx.x + 768] = src[threadIdx.x + 768];
}

// fp64 exact recompute of flagged tokens (faithful to np float64 reference)
__global__ __launch_bounds__(256)
void repair_kernel(const float* __restrict__ tokens,
                   const int* __restrict__ tarr,
                   const float* __restrict__ Wg,
                   const float* __restrict__ bg,
                   float* __restrict__ out,
                   const int* __restrict__ ws,
                   int listCap)
{
    __shared__ double red[256];
    int count = ws[0];
    if (count > listCap) count = listCap;
    const int* list = ws + 16;

    const int e    = threadIdx.x & 63;   // expert
    const int part = threadIdx.x >> 6;   // k-quarter

    for (int i = blockIdx.x; i < count; i += gridDim.x) {
        const int token = list[i];
        const float* a = tokens + (size_t)token * 1024 + part * 256;
        const float* w = Wg     + (size_t)e     * 1024 + part * 256;
        double a0 = 0.0, a1 = 0.0, a2 = 0.0, a3 = 0.0;
        for (int k = 0; k < 256; k += 4) {
            a0 = fma((double)a[k    ], (double)w[k    ], a0);
            a1 = fma((double)a[k + 1], (double)w[k + 1], a1);
            a2 = fma((double)a[k + 2], (double)w[k + 2], a2);
            a3 = fma((double)a[k + 3], (double)w[k + 3], a3);
        }
        red[threadIdx.x] = (a0 + a1) + (a2 + a3);
        __syncthreads();

        if (threadIdx.x < 64) {   // one full wave does the fp64 epilogue
            double l = ((red[e] + red[64 + e]) + (red[128 + e] + red[192 + e]))
                     + (double)bg[e];

            double mxv = l;
            #pragma unroll
            for (int off = 32; off >= 1; off >>= 1)
                mxv = fmax(mxv, __shfl_xor(mxv, off));
            double ex = exp(l - mxv);
            double s = ex;
            #pragma unroll
            for (int off = 32; off >= 1; off >>= 1)
                s += __shfl_xor(s, off);

            const double alpha = 0.15;
            double p = (1.0 - alpha) * (ex / s) + alpha / 64.0;

            double tb  = (double)tarr[token >> 12];
            double cap = 0.5 + (0.6 + 0.5) * (tb / 1000.0);
            double x = fmax(p - cap, 0.0);
            double m = p - x;
            double h = fmax(cap - m, 0.0);
            double sx = x, sh = h;
            #pragma unroll
            for (int off = 32; off >= 1; off >>= 1) {
                sx += __shfl_xor(sx, off);
                sh += __shfl_xor(sh, off);
            }
            sh = fmax(sh, 1e-8);
            double c = m + (sx / sh) * h;

            // top-2 across 64 lanes (tie -> smaller index)
            double v1 = c, v2 = -1.0e300;
            int j1 = e, j2 = 127;
            #pragma unroll
            for (int off = 1; off < 64; off <<= 1) {
                double w1 = __shfl_xor(v1, off); int k1 = __shfl_xor(j1, off);
                double w2 = __shfl_xor(v2, off); int k2 = __shfl_xor(j2, off);
                if (betterd(w1, k1, v1, j1)) {
                    if (betterd(v1, j1, w2, k2)) { v2 = v1; j2 = j1; }
                    else                         { v2 = w2; j2 = k2; }
                    v1 = w1; j1 = k1;
                } else if (betterd(w1, k1, v2, j2)) {
                    v2 = w1; j2 = k1;
                }
            }

            float g = (e == j1 || e == j2) ? (float)c : 0.0f;
            out[(size_t)token * 64 + e] = g;
        }
        __syncthreads();
    }
}

extern "C" void kernel_launch(void* const* d_in, const int* in_sizes, int n_in,
                              void* d_out, int out_size, void* d_ws, size_t ws_size,
                              hipStream_t stream) {
    const float* tokens = (const float*)d_in[0];
    const int*   t      = (const int*)d_in[1];
    const float* Wg     = (const float*)d_in[2];
    const float* bg     = (const float*)d_in[3];
    float*       outp   = (float*)d_out;

    int* wsI = (int*)d_ws;
    long long cap = (long long)(ws_size / 4) - 16;
    if (cap < 0) cap = 0;
    if (cap > 65536) cap = 65536;

    hipMemsetAsync(d_ws, 0, 64, stream);   // zero flag counter (capturable)
    router_kernel<<<dim3(65536 / 64), dim3(256), 0, stream>>>(
        tokens, t, Wg, bg, outp, wsI, wsI + 16, (int)cap);
    repair_kernel<<<dim3(256), dim3(256), 0, stream>>>(
        tokens, t, Wg, bg, outp, wsI, (int)cap);
}